// Round 1
// baseline (95.407 us; speedup 1.0000x reference)
//
#include <hip/hip_runtime.h>
#include <hip/hip_bf16.h>
#include <math.h>

typedef __attribute__((ext_vector_type(8))) short short8;
typedef __attribute__((ext_vector_type(4))) float f32x4;

#define EMBD 128
#define H1 256
#define H2 128
#define SLEN 50
#define RPB 8

__device__ __forceinline__ short f2bf(float f) {
    unsigned u = __float_as_uint(f);
    unsigned r = (u + 0x7FFFu + ((u >> 16) & 1u)) >> 16;
    return (short)r;
}

__global__ __launch_bounds__(256) void entity_encoder_kernel(
    const int* __restrict__ ids, const int* __restrict__ lens,
    const float* __restrict__ emb, const float* __restrict__ ln1g,
    const float* __restrict__ ln1b, const float* __restrict__ w1,
    const float* __restrict__ b1, const float* __restrict__ w2,
    const float* __restrict__ b2, const float* __restrict__ ln2g,
    const float* __restrict__ ln2b, const float* __restrict__ fcw,
    const float* __restrict__ fcb, float* __restrict__ out)
{
    const int tid = threadIdx.x;
    const int w  = tid >> 6;   // wave 0..3
    const int l  = tid & 63;   // lane
    const int ln = l & 15;     // lane_n (col / token-row selector)
    const int lg = l >> 4;     // lane_g (k-group / D-row group)

    __shared__ __align__(16) short x_lds[16][EMBD + 8];   // +8 shorts pad: 272B row stride
    __shared__ __align__(16) short h1_lds[16][H1 + 8];    // 528B row stride
    __shared__ float pool_lds[H2];

    // ---- preload w1/w2 MFMA B-fragments (bf16 bits) once per block ----
    // B-frag: lane holds B[k=(kt*32 + lg*8 + i)][n=col], i=0..7
    short8 w1f[4][4];
    #pragma unroll
    for (int kt = 0; kt < 4; ++kt)
      #pragma unroll
      for (int nt = 0; nt < 4; ++nt) {
        short8 v;
        int col = w * 64 + nt * 16 + ln;
        int kb  = kt * 32 + lg * 8;
        #pragma unroll
        for (int i = 0; i < 8; ++i) v[i] = f2bf(w1[(kb + i) * H1 + col]);
        w1f[kt][nt] = v;
      }
    short8 w2f[8][2];
    #pragma unroll
    for (int kt = 0; kt < 8; ++kt)
      #pragma unroll
      for (int nt = 0; nt < 2; ++nt) {
        short8 v;
        int col = w * 32 + nt * 16 + ln;
        int kb  = kt * 32 + lg * 8;
        #pragma unroll
        for (int i = 0; i < 8; ++i) v[i] = f2bf(w2[(kb + i) * H2 + col]);
        w2f[kt][nt] = v;
      }

    // per-lane constant preloads
    float g1r[8], b1r[8];
    #pragma unroll
    for (int i = 0; i < 8; ++i) { g1r[i] = ln1g[ln * 8 + i]; b1r[i] = ln1b[ln * 8 + i]; }
    float b1v[4];
    #pragma unroll
    for (int nt = 0; nt < 4; ++nt) b1v[nt] = b1[w * 64 + nt * 16 + ln];
    float b2v[2];
    #pragma unroll
    for (int nt = 0; nt < 2; ++nt) b2v[nt] = b2[w * 32 + nt * 16 + ln];
    float g2a = ln2g[l], g2c = ln2g[l + 64];
    float b2a = ln2b[l], b2c = ln2b[l + 64];
    float fwa = fcw[l],  fwc = fcw[l + 64];
    float fcb0 = fcb[0];

    for (int rr = 0; rr < RPB; ++rr) {
        int r = blockIdx.x * RPB + rr;
        int T = lens[r]; T = T < 1 ? 1 : (T > SLEN ? SLEN : T);
        int ntiles = (T + 15) >> 4;
        float pool0 = -INFINITY, pool1 = -INFINITY;

        for (int mt = 0; mt < ntiles; ++mt) {
            // ---- stage 16 tokens: (wave w, group lg) owns token w*4+lg; lanes ln cover 8 cols each
            int tok = w * 4 + lg;
            int t   = mt * 16 + tok;
            short8 xo;
            if (t < T) {
                int id = ids[r * SLEN + t];
                const float4* src = (const float4*)(emb + (size_t)id * EMBD + ln * 8);
                float4 p0 = src[0], p1 = src[1];
                float v[8] = {p0.x, p0.y, p0.z, p0.w, p1.x, p1.y, p1.z, p1.w};
                float s = 0.f, ss = 0.f;
                #pragma unroll
                for (int i = 0; i < 8; ++i) { s += v[i]; ss += v[i] * v[i]; }
                #pragma unroll
                for (int m = 1; m < 16; m <<= 1) {
                    s  += __shfl_xor(s,  m, 64);
                    ss += __shfl_xor(ss, m, 64);
                }
                float mu  = s * (1.f / 128.f);
                float var = ss * (1.f / 128.f) - mu * mu;
                float rs  = rsqrtf(var + 1e-12f);
                #pragma unroll
                for (int i = 0; i < 8; ++i)
                    xo[i] = f2bf((v[i] - mu) * rs * g1r[i] + b1r[i]);
            } else {
                #pragma unroll
                for (int i = 0; i < 8; ++i) xo[i] = 0;
            }
            *(short8*)&x_lds[tok][ln * 8] = xo;
            __syncthreads();

            // ---- GEMM1: h1[16 x 256], wave w does cols w*64..w*64+63
            f32x4 acc[4] = {{0,0,0,0},{0,0,0,0},{0,0,0,0},{0,0,0,0}};
            #pragma unroll
            for (int kt = 0; kt < 4; ++kt) {
                short8 a = *(const short8*)&x_lds[ln][kt * 32 + lg * 8];
                #pragma unroll
                for (int nt = 0; nt < 4; ++nt)
                    acc[nt] = __builtin_amdgcn_mfma_f32_16x16x32_bf16(a, w1f[kt][nt], acc[nt], 0, 0, 0);
            }
            // bias + exact GELU -> h1_lds (bf16)
            #pragma unroll
            for (int nt = 0; nt < 4; ++nt) {
                int col = w * 64 + nt * 16 + ln;
                #pragma unroll
                for (int g2 = 0; g2 < 4; ++g2) {
                    int row = lg * 4 + g2;
                    float h = acc[nt][g2] + b1v[nt];
                    h = 0.5f * h * (1.f + erff(h * 0.70710678118f));
                    h1_lds[row][col] = f2bf(h);
                }
            }
            __syncthreads();

            // ---- GEMM2: h2[16 x 128], wave w does cols w*32..w*32+31
            f32x4 acc2[2] = {{0,0,0,0},{0,0,0,0}};
            #pragma unroll
            for (int kt = 0; kt < 8; ++kt) {
                short8 a = *(const short8*)&h1_lds[ln][kt * 32 + lg * 8];
                #pragma unroll
                for (int nt = 0; nt < 2; ++nt)
                    acc2[nt] = __builtin_amdgcn_mfma_f32_16x16x32_bf16(a, w2f[kt][nt], acc2[nt], 0, 0, 0);
            }
            // ---- masked max-pool update (token trow = lg*4+g2, col = w*32+nt*16+ln)
            {
                float tm0 = -INFINITY, tm1 = -INFINITY;
                #pragma unroll
                for (int g2 = 0; g2 < 4; ++g2) {
                    int trow = lg * 4 + g2;
                    bool valid = (mt * 16 + trow) < T;
                    float h0  = acc2[0][g2] + b2v[0];
                    float h1v = acc2[1][g2] + b2v[1];
                    if (valid) { tm0 = fmaxf(tm0, h0); tm1 = fmaxf(tm1, h1v); }
                }
                tm0 = fmaxf(tm0, __shfl_xor(tm0, 16, 64));
                tm0 = fmaxf(tm0, __shfl_xor(tm0, 32, 64));
                tm1 = fmaxf(tm1, __shfl_xor(tm1, 16, 64));
                tm1 = fmaxf(tm1, __shfl_xor(tm1, 32, 64));
                pool0 = fmaxf(pool0, tm0);
                pool1 = fmaxf(pool1, tm1);
            }
            // NOTE: no sync needed here — next stage writes x_lds, which only GEMM1
            // (already fenced by the post-GEMM1 barrier) reads.
        }

        if (l < 16) {
            pool_lds[w * 32 + ln]      = pool0;
            pool_lds[w * 32 + 16 + ln] = pool1;
        }
        __syncthreads();

        // ---- LN2 + fc head (computed redundantly by all waves; lane covers cols l, l+64)
        float v0 = pool_lds[l], v1 = pool_lds[l + 64];
        float s = v0 + v1, ss = v0 * v0 + v1 * v1;
        #pragma unroll
        for (int m = 1; m < 64; m <<= 1) {
            s  += __shfl_xor(s,  m, 64);
            ss += __shfl_xor(ss, m, 64);
        }
        float mu  = s * (1.f / 128.f);
        float var = ss * (1.f / 128.f) - mu * mu;
        float rs  = rsqrtf(var + 1e-12f);
        float n0 = (v0 - mu) * rs * g2a + b2a;
        float n1 = (v1 - mu) * rs * g2c + b2c;
        float dot = n0 * fwa + n1 * fwc;
        #pragma unroll
        for (int m = 1; m < 64; m <<= 1) dot += __shfl_xor(dot, m, 64);
        if (tid == 0) out[r] = dot + fcb0;
        __syncthreads();  // protect pool_lds before next row's writes
    }
}

extern "C" void kernel_launch(void* const* d_in, const int* in_sizes, int n_in,
                              void* d_out, int out_size, void* d_ws, size_t ws_size,
                              hipStream_t stream) {
    const int*   ids  = (const int*)d_in[0];
    const int*   lens = (const int*)d_in[1];
    const float* emb  = (const float*)d_in[2];
    const float* ln1g = (const float*)d_in[3];
    const float* ln1b = (const float*)d_in[4];
    const float* w1   = (const float*)d_in[5];
    const float* b1   = (const float*)d_in[6];
    const float* w2   = (const float*)d_in[7];
    const float* b2   = (const float*)d_in[8];
    const float* ln2g = (const float*)d_in[9];
    const float* ln2b = (const float*)d_in[10];
    const float* fcw  = (const float*)d_in[11];
    const float* fcb  = (const float*)d_in[12];
    float* out = (float*)d_out;

    int nrows   = out_size;        // 4096
    int nblocks = nrows / RPB;     // 512

    hipLaunchKernelGGL(entity_encoder_kernel, dim3(nblocks), dim3(256), 0, stream,
                       ids, lens, emb, ln1g, ln1b, w1, b1, w2, b2, ln2g, ln2b, fcw, fcb, out);
}

// Round 3
// 93.180 us; speedup vs baseline: 1.0239x; 1.0239x over previous
//
#include <hip/hip_runtime.h>
#include <hip/hip_bf16.h>
#include <math.h>

typedef __attribute__((ext_vector_type(8))) short short8;
typedef __attribute__((ext_vector_type(4))) float f32x4;

#define EMBD 128
#define H1 256
#define H2 128
#define SLEN 50

__device__ __forceinline__ short f2bf(float f) {
    unsigned u = __float_as_uint(f);
    unsigned r = (u + 0x7FFFu + ((u >> 16) & 1u)) >> 16;
    return (short)r;
}

// Raw barrier WITHOUT vmcnt drain: LDS ordering only (lgkmcnt), so the
// one-tile-ahead embedding prefetch stays in flight across it.
#define BARRIER_LDS() asm volatile("s_waitcnt lgkmcnt(0)\n\ts_barrier" ::: "memory")

// ---------------------------------------------------------------------------
// Prep: convert w1[128][256], w2[256][128] (fp32 row-major) into bf16 MFMA
// B-fragments laid out so the main kernel's loads are wave-coalesced 16B.
//   w1 frag f = ((w*4+kt)*4+nt)*64 + lane   (4096 frags, 64 KB at ws[0])
//   w2 frag f = ((w*8+kt)*2+nt)*64 + lane   (4096 frags, 64 KB at ws[4096])
// Fragment content: lane (lg=lane>>4, ln=lane&15) holds B[kt*32+lg*8+i][col]
// ---------------------------------------------------------------------------
__global__ __launch_bounds__(256) void prep_weights(
    const float* __restrict__ w1, const float* __restrict__ w2,
    short8* __restrict__ ws)
{
    int f = blockIdx.x * 256 + threadIdx.x;   // 0..8191
    short8 v;
    if (f < 4096) {
        int lane = f & 63;
        int nt = (f >> 6) & 3, kt = (f >> 8) & 3, w = (f >> 10) & 3;
        int col = w * 64 + nt * 16 + (lane & 15);
        int kb  = kt * 32 + (lane >> 4) * 8;
        #pragma unroll
        for (int i = 0; i < 8; ++i) v[i] = f2bf(w1[(size_t)(kb + i) * H1 + col]);
        ws[f] = v;
    } else {
        int f2 = f - 4096;
        int lane = f2 & 63;
        int nt = (f2 >> 6) & 1, kt = (f2 >> 7) & 7, w = (f2 >> 10) & 3;
        int col = w * 32 + nt * 16 + (lane & 15);
        int kb  = kt * 32 + (lane >> 4) * 8;
        #pragma unroll
        for (int i = 0; i < 8; ++i) v[i] = f2bf(w2[(size_t)(kb + i) * H2 + col]);
        ws[4096 + f2] = v;
    }
}

// ---------------------------------------------------------------------------
// Main: one block per row (4096 blocks x 256 threads).
// ---------------------------------------------------------------------------
__global__ __launch_bounds__(256) void entity_encoder_kernel(
    const int* __restrict__ ids, const int* __restrict__ lens,
    const float* __restrict__ emb, const float* __restrict__ ln1g,
    const float* __restrict__ ln1b, const float* __restrict__ b1,
    const float* __restrict__ b2, const float* __restrict__ ln2g,
    const float* __restrict__ ln2b, const float* __restrict__ fcw,
    const float* __restrict__ fcb, const short8* __restrict__ wfrag,
    float* __restrict__ out)
{
    const int tid = threadIdx.x;
    const int w  = tid >> 6;   // wave 0..3
    const int l  = tid & 63;   // lane
    const int ln = l & 15;
    const int lg = l >> 4;

    __shared__ __align__(16) short x_lds[16][EMBD + 8];
    __shared__ __align__(16) short h1_lds[16][H1 + 8];
    __shared__ float pool_lds[H2];

    // ---- weight fragments: 32 coalesced 16B loads (L2-hot after block 0) ----
    short8 w1f[4][4];
    #pragma unroll
    for (int kt = 0; kt < 4; ++kt)
      #pragma unroll
      for (int nt = 0; nt < 4; ++nt)
        w1f[kt][nt] = wfrag[((w * 4 + kt) * 4 + nt) * 64 + l];
    short8 w2f[8][2];
    #pragma unroll
    for (int kt = 0; kt < 8; ++kt)
      #pragma unroll
      for (int nt = 0; nt < 2; ++nt)
        w2f[kt][nt] = wfrag[4096 + ((w * 8 + kt) * 2 + nt) * 64 + l];

    float g1r[8], b1r[8];
    #pragma unroll
    for (int i = 0; i < 8; ++i) { g1r[i] = ln1g[ln * 8 + i]; b1r[i] = ln1b[ln * 8 + i]; }
    float b1v[4];
    #pragma unroll
    for (int nt = 0; nt < 4; ++nt) b1v[nt] = b1[w * 64 + nt * 16 + ln];
    float b2v[2];
    #pragma unroll
    for (int nt = 0; nt < 2; ++nt) b2v[nt] = b2[w * 32 + nt * 16 + ln];
    float g2a = ln2g[l], g2c = ln2g[l + 64];
    float b2a = ln2b[l], b2c = ln2b[l + 64];
    float fwa = fcw[l],  fwc = fcw[l + 64];
    float fcb0 = fcb[0];

    const int r = blockIdx.x;
    int T = lens[r]; T = T < 1 ? 1 : (T > SLEN ? SLEN : T);
    const int ntiles = (T + 15) >> 4;
    float pool0 = -INFINITY, pool1 = -INFINITY;

    const int tok = w * 4 + lg;   // token-in-tile owned by this 16-lane group

    // ---- prefetch tile 0's embedding rows ----
    float4 pa0, pa1; bool va;
    {
        int t = tok; va = (t < T);
        if (va) {
            int id = ids[r * SLEN + t];
            const float4* src = (const float4*)(emb + (size_t)id * EMBD + ln * 8);
            pa0 = src[0]; pa1 = src[1];
        }
    }

    for (int mt = 0; mt < ntiles; ++mt) {
        // ---- LN1 on prefetched tile -> bf16 -> x_lds ----
        short8 xo;
        if (va) {
            float v[8] = {pa0.x, pa0.y, pa0.z, pa0.w, pa1.x, pa1.y, pa1.z, pa1.w};
            float s = 0.f, ss = 0.f;
            #pragma unroll
            for (int i = 0; i < 8; ++i) { s += v[i]; ss += v[i] * v[i]; }
            #pragma unroll
            for (int m = 1; m < 16; m <<= 1) {
                s  += __shfl_xor(s,  m, 64);
                ss += __shfl_xor(ss, m, 64);
            }
            float mu  = s * (1.f / 128.f);
            float var = ss * (1.f / 128.f) - mu * mu;
            float rs  = rsqrtf(var + 1e-12f);
            #pragma unroll
            for (int i = 0; i < 8; ++i)
                xo[i] = f2bf((v[i] - mu) * rs * g1r[i] + b1r[i]);
        } else {
            #pragma unroll
            for (int i = 0; i < 8; ++i) xo[i] = 0;
        }
        *(short8*)&x_lds[tok][ln * 8] = xo;

        // ---- issue next tile's gather (stays in flight across raw barriers) ----
        float4 pb0, pb1; bool vb = false;
        {
            int tn = (mt + 1) * 16 + tok;
            if (mt + 1 < ntiles && tn < T) {
                vb = true;
                int id = ids[r * SLEN + tn];
                const float4* src = (const float4*)(emb + (size_t)id * EMBD + ln * 8);
                pb0 = src[0]; pb1 = src[1];
            }
        }

        BARRIER_LDS();   // x_lds ready (no vmcnt drain)

        // ---- GEMM1: wave w computes cols w*64..w*64+63 ----
        f32x4 acc[4] = {{0,0,0,0},{0,0,0,0},{0,0,0,0},{0,0,0,0}};
        #pragma unroll
        for (int kt = 0; kt < 4; ++kt) {
            short8 a = *(const short8*)&x_lds[ln][kt * 32 + lg * 8];
            #pragma unroll
            for (int nt = 0; nt < 4; ++nt)
                acc[nt] = __builtin_amdgcn_mfma_f32_16x16x32_bf16(a, w1f[kt][nt], acc[nt], 0, 0, 0);
        }
        // bias + exact-erf GELU -> h1_lds (bf16)  [R1-proven numerics]
        #pragma unroll
        for (int nt = 0; nt < 4; ++nt) {
            int col = w * 64 + nt * 16 + ln;
            #pragma unroll
            for (int g2 = 0; g2 < 4; ++g2) {
                int row = lg * 4 + g2;
                float h = acc[nt][g2] + b1v[nt];
                h = 0.5f * h * (1.f + erff(h * 0.70710678118f));
                h1_lds[row][col] = f2bf(h);
            }
        }

        BARRIER_LDS();   // h1_lds ready (no vmcnt drain)

        // ---- GEMM2: wave w computes cols w*32..w*32+31 ----
        f32x4 acc2[2] = {{0,0,0,0},{0,0,0,0}};
        #pragma unroll
        for (int kt = 0; kt < 8; ++kt) {
            short8 a = *(const short8*)&h1_lds[ln][kt * 32 + lg * 8];
            #pragma unroll
            for (int nt = 0; nt < 2; ++nt)
                acc2[nt] = __builtin_amdgcn_mfma_f32_16x16x32_bf16(a, w2f[kt][nt], acc2[nt], 0, 0, 0);
        }
        // ---- masked max-pool (token = lg*4+g2) ----
        {
            float tm0 = -INFINITY, tm1 = -INFINITY;
            #pragma unroll
            for (int g2 = 0; g2 < 4; ++g2) {
                int trow = lg * 4 + g2;
                bool valid = (mt * 16 + trow) < T;
                float h0  = acc2[0][g2] + b2v[0];
                float h1v = acc2[1][g2] + b2v[1];
                if (valid) { tm0 = fmaxf(tm0, h0); tm1 = fmaxf(tm1, h1v); }
            }
            tm0 = fmaxf(tm0, __shfl_xor(tm0, 16, 64));
            tm0 = fmaxf(tm0, __shfl_xor(tm0, 32, 64));
            tm1 = fmaxf(tm1, __shfl_xor(tm1, 16, 64));
            tm1 = fmaxf(tm1, __shfl_xor(tm1, 32, 64));
            pool0 = fmaxf(pool0, tm0);
            pool1 = fmaxf(pool1, tm1);
        }

        if (vb) { pa0 = pb0; pa1 = pb1; }
        va = vb;
        // next x_lds write is safe: GEMM1 readers fenced by the 2nd BARRIER_LDS
    }

    if (l < 16) {
        pool_lds[w * 32 + ln]      = pool0;
        pool_lds[w * 32 + 16 + ln] = pool1;
    }
    __syncthreads();

    // ---- LN2 + fc head ----
    float v0 = pool_lds[l], v1 = pool_lds[l + 64];
    float s = v0 + v1, ss = v0 * v0 + v1 * v1;
    #pragma unroll
    for (int m = 1; m < 64; m <<= 1) {
        s  += __shfl_xor(s,  m, 64);
        ss += __shfl_xor(ss, m, 64);
    }
    float mu  = s * (1.f / 128.f);
    float var = ss * (1.f / 128.f) - mu * mu;
    float rs  = rsqrtf(var + 1e-12f);
    float n0 = (v0 - mu) * rs * g2a + b2a;
    float n1 = (v1 - mu) * rs * g2c + b2c;
    float dot = n0 * fwa + n1 * fwc;
    #pragma unroll
    for (int m = 1; m < 64; m <<= 1) dot += __shfl_xor(dot, m, 64);
    if (tid == 0) out[r] = dot + fcb0;
}

extern "C" void kernel_launch(void* const* d_in, const int* in_sizes, int n_in,
                              void* d_out, int out_size, void* d_ws, size_t ws_size,
                              hipStream_t stream) {
    const int*   ids  = (const int*)d_in[0];
    const int*   lens = (const int*)d_in[1];
    const float* emb  = (const float*)d_in[2];
    const float* ln1g = (const float*)d_in[3];
    const float* ln1b = (const float*)d_in[4];
    const float* w1   = (const float*)d_in[5];
    const float* b1   = (const float*)d_in[6];
    const float* w2   = (const float*)d_in[7];
    const float* b2   = (const float*)d_in[8];
    const float* ln2g = (const float*)d_in[9];
    const float* ln2b = (const float*)d_in[10];
    const float* fcw  = (const float*)d_in[11];
    const float* fcb  = (const float*)d_in[12];
    float* out = (float*)d_out;
    short8* ws = (short8*)d_ws;   // needs 128 KiB

    hipLaunchKernelGGL(prep_weights, dim3(32), dim3(256), 0, stream, w1, w2, ws);

    int nblocks = out_size;   // 4096 rows, 1 row per block
    hipLaunchKernelGGL(entity_encoder_kernel, dim3(nblocks), dim3(256), 0, stream,
                       ids, lens, emb, ln1g, ln1b, b1, b2, ln2g, ln2b, fcw, fcb,
                       ws, out);
}

// Round 5
// 74.527 us; speedup vs baseline: 1.2802x; 1.2503x over previous
//
#include <hip/hip_runtime.h>
#include <hip/hip_bf16.h>
#include <math.h>

typedef __attribute__((ext_vector_type(8))) short short8;
typedef __attribute__((ext_vector_type(4))) float f32x4;

#define EMBD 128
#define H1 256
#define H2 128
#define SLEN 50

__device__ __forceinline__ short f2bf(float f) {
    __hip_bfloat16 h = __float2bfloat16(f);   // RNE; compiler packs pairs via v_cvt_pk_bf16_f32
    return *reinterpret_cast<short*>(&h);
}

// Branch-free GELU, exact-erf form via Abramowitz-Stegun 7.1.26 (|err|<=1.5e-7).
// erf(|z|) = 1 - P(t)*exp(-z^2), t = 1/(1+0.3275911|z|), z = h/sqrt(2).
// gelu(h) = 0.5h(1+erf(z)) = 0.5h + 0.5|h|*erf(|z|)   [since h*sign(h)=|h|]
__device__ __forceinline__ float gelu_exact(float h) {
    float ah = fabsf(h);
    float d  = fmaf(0.23163845f, ah, 1.0f);          // 0.3275911/sqrt(2) * |h| + 1
    float t;
    asm("v_rcp_f32 %0, %1" : "=v"(t) : "v"(d));
    float p = fmaf(1.061405429f, t, -1.453152027f);
    p = fmaf(p, t, 1.421413741f);
    p = fmaf(p, t, -0.284496736f);
    p = fmaf(p, t, 0.254829592f);
    p = p * t;
    float e;                                          // v_exp_f32 computes 2^x
    float x2 = h * h * -0.72134752f;                  // -h^2/2 * log2(e)
    asm("v_exp_f32 %0, %1" : "=v"(e) : "v"(x2));
    float er = fmaf(-p, e, 1.0f);                    // erf(|z|)
    return fmaf(0.5f * ah, er, 0.5f * h);
}

// Raw barrier WITHOUT vmcnt drain: LDS ordering only (lgkmcnt), so the
// one-tile-ahead embedding prefetch stays in flight across it.
#define BARRIER_LDS() asm volatile("s_waitcnt lgkmcnt(0)\n\ts_barrier" ::: "memory")

// ---------------------------------------------------------------------------
// Prep: convert w1[128][256], w2[256][128] (fp32 row-major) into bf16 MFMA
// B-fragments laid out so the main kernel's loads are wave-coalesced 16B.
//   w1 frag f = ((w*4+kt)*4+nt)*64 + lane   (4096 frags, 64 KB at ws[0])
//   w2 frag f = ((w*8+kt)*2+nt)*64 + lane   (4096 frags, 64 KB at ws[4096])
// Fragment content: lane (lg=lane>>4, ln=lane&15) holds B[kt*32+lg*8+i][col]
// ---------------------------------------------------------------------------
__global__ __launch_bounds__(256) void prep_weights(
    const float* __restrict__ w1, const float* __restrict__ w2,
    short8* __restrict__ ws)
{
    int f = blockIdx.x * 256 + threadIdx.x;   // 0..8191
    short8 v;
    if (f < 4096) {
        int lane = f & 63;
        int nt = (f >> 6) & 3, kt = (f >> 8) & 3, w = (f >> 10) & 3;
        int col = w * 64 + nt * 16 + (lane & 15);
        int kb  = kt * 32 + (lane >> 4) * 8;
        #pragma unroll
        for (int i = 0; i < 8; ++i) v[i] = f2bf(w1[(size_t)(kb + i) * H1 + col]);
        ws[f] = v;
    } else {
        int f2 = f - 4096;
        int lane = f2 & 63;
        int nt = (f2 >> 6) & 1, kt = (f2 >> 7) & 7, w = (f2 >> 10) & 3;
        int col = w * 32 + nt * 16 + (lane & 15);
        int kb  = kt * 32 + (lane >> 4) * 8;
        #pragma unroll
        for (int i = 0; i < 8; ++i) v[i] = f2bf(w2[(size_t)(kb + i) * H2 + col]);
        ws[4096 + f2] = v;
    }
}

// ---------------------------------------------------------------------------
// Main: one block per row (4096 blocks x 256 threads).
// ---------------------------------------------------------------------------
__global__ __launch_bounds__(256) void entity_encoder_kernel(
    const int* __restrict__ ids, const int* __restrict__ lens,
    const float* __restrict__ emb, const float* __restrict__ ln1g,
    const float* __restrict__ ln1b, const float* __restrict__ b1,
    const float* __restrict__ b2, const float* __restrict__ ln2g,
    const float* __restrict__ ln2b, const float* __restrict__ fcw,
    const float* __restrict__ fcb, const short8* __restrict__ wfrag,
    float* __restrict__ out)
{
    const int tid = threadIdx.x;
    const int w  = tid >> 6;   // wave 0..3
    const int l  = tid & 63;   // lane
    const int ln = l & 15;
    const int lg = l >> 4;

    __shared__ __align__(16) short x_lds[16][EMBD + 8];
    __shared__ __align__(16) short h1_lds[16][H1 + 8];
    __shared__ float pool_lds[H2];

    // ---- weight fragments: 32 coalesced 16B loads (L2-hot after block 0) ----
    short8 w1f[4][4];
    #pragma unroll
    for (int kt = 0; kt < 4; ++kt)
      #pragma unroll
      for (int nt = 0; nt < 4; ++nt)
        w1f[kt][nt] = wfrag[((w * 4 + kt) * 4 + nt) * 64 + l];
    short8 w2f[8][2];
    #pragma unroll
    for (int kt = 0; kt < 8; ++kt)
      #pragma unroll
      for (int nt = 0; nt < 2; ++nt)
        w2f[kt][nt] = wfrag[4096 + ((w * 8 + kt) * 2 + nt) * 64 + l];

    float g1r[8], b1r[8];
    #pragma unroll
    for (int i = 0; i < 8; ++i) { g1r[i] = ln1g[ln * 8 + i]; b1r[i] = ln1b[ln * 8 + i]; }
    float b1v[4];
    #pragma unroll
    for (int nt = 0; nt < 4; ++nt) b1v[nt] = b1[w * 64 + nt * 16 + ln];
    float b2v[2];
    #pragma unroll
    for (int nt = 0; nt < 2; ++nt) b2v[nt] = b2[w * 32 + nt * 16 + ln];
    float g2a = ln2g[l], g2c = ln2g[l + 64];
    float b2a = ln2b[l], b2c = ln2b[l + 64];
    float fwa = fcw[l],  fwc = fcw[l + 64];
    float fcb0 = fcb[0];

    const int r = blockIdx.x;
    int T = lens[r]; T = T < 1 ? 1 : (T > SLEN ? SLEN : T);
    const int ntiles = (T + 15) >> 4;
    float pool0 = -INFINITY, pool1 = -INFINITY;

    const int tok = w * 4 + lg;   // token-in-tile owned by this 16-lane group

    // ---- prefetch tile 0's embedding rows ----
    float4 pa0, pa1; bool va;
    {
        int t = tok; va = (t < T);
        if (va) {
            int id = ids[r * SLEN + t];
            const float4* src = (const float4*)(emb + (size_t)id * EMBD + ln * 8);
            pa0 = src[0]; pa1 = src[1];
        }
    }

    for (int mt = 0; mt < ntiles; ++mt) {
        // ---- LN1 on prefetched tile -> bf16 -> x_lds ----
        short8 xo;
        if (va) {
            float v[8] = {pa0.x, pa0.y, pa0.z, pa0.w, pa1.x, pa1.y, pa1.z, pa1.w};
            float s = 0.f, ss = 0.f;
            #pragma unroll
            for (int i = 0; i < 8; ++i) { s += v[i]; ss += v[i] * v[i]; }
            #pragma unroll
            for (int m = 1; m < 16; m <<= 1) {
                s  += __shfl_xor(s,  m, 64);
                ss += __shfl_xor(ss, m, 64);
            }
            float mu  = s * (1.f / 128.f);
            float var = ss * (1.f / 128.f) - mu * mu;
            float rs  = rsqrtf(var + 1e-12f);
            #pragma unroll
            for (int i = 0; i < 8; ++i)
                xo[i] = f2bf((v[i] - mu) * rs * g1r[i] + b1r[i]);
        } else {
            #pragma unroll
            for (int i = 0; i < 8; ++i) xo[i] = 0;
        }
        *(short8*)&x_lds[tok][ln * 8] = xo;

        // ---- issue next tile's gather (stays in flight across raw barriers) ----
        float4 pb0, pb1; bool vb = false;
        {
            int tn = (mt + 1) * 16 + tok;
            if (mt + 1 < ntiles && tn < T) {
                vb = true;
                int id = ids[r * SLEN + tn];
                const float4* src = (const float4*)(emb + (size_t)id * EMBD + ln * 8);
                pb0 = src[0]; pb1 = src[1];
            }
        }

        BARRIER_LDS();   // x_lds ready (no vmcnt drain)

        // ---- GEMM1: wave w computes cols w*64..w*64+63 ----
        f32x4 acc[4] = {{0,0,0,0},{0,0,0,0},{0,0,0,0},{0,0,0,0}};
        #pragma unroll
        for (int kt = 0; kt < 4; ++kt) {
            short8 a = *(const short8*)&x_lds[ln][kt * 32 + lg * 8];
            #pragma unroll
            for (int nt = 0; nt < 4; ++nt)
                acc[nt] = __builtin_amdgcn_mfma_f32_16x16x32_bf16(a, w1f[kt][nt], acc[nt], 0, 0, 0);
        }
        // bias + branch-free exact-erf GELU -> h1_lds (bf16)
        #pragma unroll
        for (int nt = 0; nt < 4; ++nt) {
            int col = w * 64 + nt * 16 + ln;
            #pragma unroll
            for (int g2 = 0; g2 < 4; ++g2) {
                int row = lg * 4 + g2;
                float h = acc[nt][g2] + b1v[nt];
                h1_lds[row][col] = f2bf(gelu_exact(h));
            }
        }

        BARRIER_LDS();   // h1_lds ready (no vmcnt drain)

        // ---- GEMM2: wave w computes cols w*32..w*32+31 ----
        f32x4 acc2[2] = {{0,0,0,0},{0,0,0,0}};
        #pragma unroll
        for (int kt = 0; kt < 8; ++kt) {
            short8 a = *(const short8*)&h1_lds[ln][kt * 32 + lg * 8];
            #pragma unroll
            for (int nt = 0; nt < 2; ++nt)
                acc2[nt] = __builtin_amdgcn_mfma_f32_16x16x32_bf16(a, w2f[kt][nt], acc2[nt], 0, 0, 0);
        }
        // ---- masked max-pool (token = lg*4+g2) ----
        {
            float tm0 = -INFINITY, tm1 = -INFINITY;
            #pragma unroll
            for (int g2 = 0; g2 < 4; ++g2) {
                int trow = lg * 4 + g2;
                bool valid = (mt * 16 + trow) < T;
                float h0  = acc2[0][g2] + b2v[0];
                float h1v = acc2[1][g2] + b2v[1];
                if (valid) { tm0 = fmaxf(tm0, h0); tm1 = fmaxf(tm1, h1v); }
            }
            tm0 = fmaxf(tm0, __shfl_xor(tm0, 16, 64));
            tm0 = fmaxf(tm0, __shfl_xor(tm0, 32, 64));
            tm1 = fmaxf(tm1, __shfl_xor(tm1, 16, 64));
            tm1 = fmaxf(tm1, __shfl_xor(tm1, 32, 64));
            pool0 = fmaxf(pool0, tm0);
            pool1 = fmaxf(pool1, tm1);
        }

        if (vb) { pa0 = pb0; pa1 = pb1; }
        va = vb;
        // next x_lds write is safe: GEMM1 readers fenced by the 2nd BARRIER_LDS
    }

    if (l < 16) {
        pool_lds[w * 32 + ln]      = pool0;
        pool_lds[w * 32 + 16 + ln] = pool1;
    }
    __syncthreads();

    // ---- LN2 + fc head ----
    float v0 = pool_lds[l], v1 = pool_lds[l + 64];
    float s = v0 + v1, ss = v0 * v0 + v1 * v1;
    #pragma unroll
    for (int m = 1; m < 64; m <<= 1) {
        s  += __shfl_xor(s,  m, 64);
        ss += __shfl_xor(ss, m, 64);
    }
    float mu  = s * (1.f / 128.f);
    float var = ss * (1.f / 128.f) - mu * mu;
    float rs  = rsqrtf(var + 1e-12f);
    float n0 = (v0 - mu) * rs * g2a + b2a;
    float n1 = (v1 - mu) * rs * g2c + b2c;
    float dot = n0 * fwa + n1 * fwc;
    #pragma unroll
    for (int m = 1; m < 64; m <<= 1) dot += __shfl_xor(dot, m, 64);
    if (tid == 0) out[r] = dot + fcb0;
}

extern "C" void kernel_launch(void* const* d_in, const int* in_sizes, int n_in,
                              void* d_out, int out_size, void* d_ws, size_t ws_size,
                              hipStream_t stream) {
    const int*   ids  = (const int*)d_in[0];
    const int*   lens = (const int*)d_in[1];
    const float* emb  = (const float*)d_in[2];
    const float* ln1g = (const float*)d_in[3];
    const float* ln1b = (const float*)d_in[4];
    const float* w1   = (const float*)d_in[5];
    const float* b1   = (const float*)d_in[6];
    const float* w2   = (const float*)d_in[7];
    const float* b2   = (const float*)d_in[8];
    const float* ln2g = (const float*)d_in[9];
    const float* ln2b = (const float*)d_in[10];
    const float* fcw  = (const float*)d_in[11];
    const float* fcb  = (const float*)d_in[12];
    float* out = (float*)d_out;
    short8* ws = (short8*)d_ws;   // needs 128 KiB

    hipLaunchKernelGGL(prep_weights, dim3(32), dim3(256), 0, stream, w1, w2, ws);

    int nblocks = out_size;   // 4096 rows, 1 row per block
    hipLaunchKernelGGL(entity_encoder_kernel, dim3(nblocks), dim3(256), 0, stream,
                       ids, lens, emb, ln1g, ln1b, b1, b2, ln2g, ln2b, fcw, fcb,
                       ws, out);
}

// Round 6
// 70.417 us; speedup vs baseline: 1.3549x; 1.0584x over previous
//
#include <hip/hip_runtime.h>
#include <hip/hip_bf16.h>
#include <math.h>

typedef __attribute__((ext_vector_type(8))) short short8;
typedef __attribute__((ext_vector_type(4))) float f32x4;

#define EMBD 128
#define H1 256
#define H2 128
#define SLEN 50
#define NR 4            // rows per block (grid = 4096/NR = 1024)

__device__ __forceinline__ short f2bf(float f) {
    __hip_bfloat16 h = __float2bfloat16(f);   // RNE; compiler packs pairs via v_cvt_pk_bf16_f32
    return *reinterpret_cast<short*>(&h);
}

// Branch-free GELU, exact-erf form via Abramowitz-Stegun 7.1.26 (|err|<=1.5e-7).
__device__ __forceinline__ float gelu_exact(float h) {
    float ah = fabsf(h);
    float d  = fmaf(0.23163845f, ah, 1.0f);
    float t;
    asm("v_rcp_f32 %0, %1" : "=v"(t) : "v"(d));
    float p = fmaf(1.061405429f, t, -1.453152027f);
    p = fmaf(p, t, 1.421413741f);
    p = fmaf(p, t, -0.284496736f);
    p = fmaf(p, t, 0.254829592f);
    p = p * t;
    float e;                                   // v_exp_f32 computes 2^x
    float x2 = h * h * -0.72134752f;           // -h^2/2 * log2(e)
    asm("v_exp_f32 %0, %1" : "=v"(e) : "v"(x2));
    float er = fmaf(-p, e, 1.0f);
    return fmaf(0.5f * ah, er, 0.5f * h);
}

// Raw barrier WITHOUT vmcnt drain: LDS ordering only (lgkmcnt), so in-flight
// global prefetches survive the barrier.
#define BARRIER_LDS() asm volatile("s_waitcnt lgkmcnt(0)\n\ts_barrier" ::: "memory")

// ---------------------------------------------------------------------------
// Prep: w1/w2 fp32 row-major -> bf16 MFMA B-fragments (see R3 comments).
// ---------------------------------------------------------------------------
__global__ __launch_bounds__(256) void prep_weights(
    const float* __restrict__ w1, const float* __restrict__ w2,
    short8* __restrict__ ws)
{
    int f = blockIdx.x * 256 + threadIdx.x;   // 0..8191
    short8 v;
    if (f < 4096) {
        int lane = f & 63;
        int nt = (f >> 6) & 3, kt = (f >> 8) & 3, w = (f >> 10) & 3;
        int col = w * 64 + nt * 16 + (lane & 15);
        int kb  = kt * 32 + (lane >> 4) * 8;
        #pragma unroll
        for (int i = 0; i < 8; ++i) v[i] = f2bf(w1[(size_t)(kb + i) * H1 + col]);
        ws[f] = v;
    } else {
        int f2 = f - 4096;
        int lane = f2 & 63;
        int nt = (f2 >> 6) & 1, kt = (f2 >> 7) & 7, w = (f2 >> 10) & 3;
        int col = w * 32 + nt * 16 + (lane & 15);
        int kb  = kt * 32 + (lane >> 4) * 8;
        #pragma unroll
        for (int i = 0; i < 8; ++i) v[i] = f2bf(w2[(size_t)(kb + i) * H2 + col]);
        ws[4096 + f2] = v;
    }
}

// ---------------------------------------------------------------------------
// Main: 1024 persistent blocks x 256 threads, NR=4 rows each (strided).
// ---------------------------------------------------------------------------
__global__ __launch_bounds__(256) void entity_encoder_kernel(
    const int* __restrict__ ids, const int* __restrict__ lens,
    const float* __restrict__ emb, const float* __restrict__ ln1g,
    const float* __restrict__ ln1b, const float* __restrict__ b1,
    const float* __restrict__ b2, const float* __restrict__ ln2g,
    const float* __restrict__ ln2b, const float* __restrict__ fcw,
    const float* __restrict__ fcb, const short8* __restrict__ wfrag,
    float* __restrict__ out)
{
    const int tid = threadIdx.x;
    const int w  = tid >> 6;   // wave 0..3
    const int l  = tid & 63;   // lane
    const int ln = l & 15;
    const int lg = l >> 4;

    __shared__ __align__(16) short x_lds[16][EMBD + 8];
    __shared__ __align__(16) short h1_lds[16][H1 + 8];
    __shared__ float pool_lds[H2];

    // ---- weight fragments: 32 coalesced 16B loads, ONCE per block (4 rows) ----
    short8 w1f[4][4];
    #pragma unroll
    for (int kt = 0; kt < 4; ++kt)
      #pragma unroll
      for (int nt = 0; nt < 4; ++nt)
        w1f[kt][nt] = wfrag[((w * 4 + kt) * 4 + nt) * 64 + l];
    short8 w2f[8][2];
    #pragma unroll
    for (int kt = 0; kt < 8; ++kt)
      #pragma unroll
      for (int nt = 0; nt < 2; ++nt)
        w2f[kt][nt] = wfrag[4096 + ((w * 8 + kt) * 2 + nt) * 64 + l];

    float g1r[8], b1r[8];
    #pragma unroll
    for (int i = 0; i < 8; ++i) { g1r[i] = ln1g[ln * 8 + i]; b1r[i] = ln1b[ln * 8 + i]; }
    float b1v[4];
    #pragma unroll
    for (int nt = 0; nt < 4; ++nt) b1v[nt] = b1[w * 64 + nt * 16 + ln];
    float b2v[2];
    #pragma unroll
    for (int nt = 0; nt < 2; ++nt) b2v[nt] = b2[w * 32 + nt * 16 + ln];
    float g2a = ln2g[l], g2c = ln2g[l + 64];
    float b2a = ln2b[l], b2c = ln2b[l + 64];
    float fwa = fcw[l],  fwc = fcw[l + 64];
    float fcb0 = fcb[0];

    const int stride = gridDim.x;              // 1024
    const int tok = w * 4 + lg;                // token-in-tile of this 16-lane group

    // ---- per-block row list + lengths (uniform scalar loads) ----
    int rows[NR], Ts[NR];
    #pragma unroll
    for (int i = 0; i < NR; ++i) {
        rows[i] = blockIdx.x + i * stride;
        int T = lens[rows[i]];
        Ts[i] = T < 1 ? 1 : (T > SLEN ? SLEN : T);
    }

    // ---- prefetch row 0, tile 0 ----
    float4 pa0, pa1; bool va;
    {
        va = (tok < Ts[0]);
        if (va) {
            int id = ids[rows[0] * SLEN + tok];
            const float4* src = (const float4*)(emb + (size_t)id * EMBD + ln * 8);
            pa0 = src[0]; pa1 = src[1];
        }
    }

    for (int i = 0; i < NR; ++i) {
        const int r = rows[i];
        const int T = Ts[i];
        const int ntiles = (T + 15) >> 4;
        float pool0 = -INFINITY, pool1 = -INFINITY;

        for (int mt = 0; mt < ntiles; ++mt) {
            // ---- LN1 on prefetched tile -> bf16 -> x_lds ----
            short8 xo;
            if (va) {
                float v[8] = {pa0.x, pa0.y, pa0.z, pa0.w, pa1.x, pa1.y, pa1.z, pa1.w};
                float s = 0.f, ss = 0.f;
                #pragma unroll
                for (int k = 0; k < 8; ++k) { s += v[k]; ss += v[k] * v[k]; }
                #pragma unroll
                for (int m = 1; m < 16; m <<= 1) {
                    s  += __shfl_xor(s,  m, 64);
                    ss += __shfl_xor(ss, m, 64);
                }
                float mu  = s * (1.f / 128.f);
                float var = ss * (1.f / 128.f) - mu * mu;
                float rs  = rsqrtf(var + 1e-12f);
                #pragma unroll
                for (int k = 0; k < 8; ++k)
                    xo[k] = f2bf((v[k] - mu) * rs * g1r[k] + b1r[k]);
            } else {
                #pragma unroll
                for (int k = 0; k < 8; ++k) xo[k] = 0;
            }
            *(short8*)&x_lds[tok][ln * 8] = xo;

            // ---- issue next gather: tile mt+1 of this row, else tile 0 of next row ----
            float4 pb0, pb1; bool vb = false;
            {
                int ni = i, nmt = mt + 1;
                if (nmt >= ntiles) { ni = i + 1; nmt = 0; }
                if (ni < NR) {
                    int tn = nmt * 16 + tok;
                    if (tn < Ts[ni]) {
                        vb = true;
                        int id = ids[rows[ni] * SLEN + tn];
                        const float4* src = (const float4*)(emb + (size_t)id * EMBD + ln * 8);
                        pb0 = src[0]; pb1 = src[1];
                    }
                }
            }

            BARRIER_LDS();   // x_lds ready (no vmcnt drain)

            // ---- GEMM1: wave w computes cols w*64..w*64+63 ----
            f32x4 acc[4] = {{0,0,0,0},{0,0,0,0},{0,0,0,0},{0,0,0,0}};
            #pragma unroll
            for (int kt = 0; kt < 4; ++kt) {
                short8 a = *(const short8*)&x_lds[ln][kt * 32 + lg * 8];
                #pragma unroll
                for (int nt = 0; nt < 4; ++nt)
                    acc[nt] = __builtin_amdgcn_mfma_f32_16x16x32_bf16(a, w1f[kt][nt], acc[nt], 0, 0, 0);
            }
            // bias + branch-free exact-erf GELU -> h1_lds (bf16)
            #pragma unroll
            for (int nt = 0; nt < 4; ++nt) {
                int col = w * 64 + nt * 16 + ln;
                #pragma unroll
                for (int g2 = 0; g2 < 4; ++g2) {
                    int row = lg * 4 + g2;
                    float h = acc[nt][g2] + b1v[nt];
                    h1_lds[row][col] = f2bf(gelu_exact(h));
                }
            }

            BARRIER_LDS();   // h1_lds ready (no vmcnt drain)

            // ---- GEMM2: wave w computes cols w*32..w*32+31 ----
            f32x4 acc2[2] = {{0,0,0,0},{0,0,0,0}};
            #pragma unroll
            for (int kt = 0; kt < 8; ++kt) {
                short8 a = *(const short8*)&h1_lds[ln][kt * 32 + lg * 8];
                #pragma unroll
                for (int nt = 0; nt < 2; ++nt)
                    acc2[nt] = __builtin_amdgcn_mfma_f32_16x16x32_bf16(a, w2f[kt][nt], acc2[nt], 0, 0, 0);
            }
            // ---- masked max-pool (token = lg*4+g2) ----
            {
                float tm0 = -INFINITY, tm1 = -INFINITY;
                #pragma unroll
                for (int g2 = 0; g2 < 4; ++g2) {
                    int trow = lg * 4 + g2;
                    bool valid = (mt * 16 + trow) < T;
                    float h0  = acc2[0][g2] + b2v[0];
                    float h1v = acc2[1][g2] + b2v[1];
                    if (valid) { tm0 = fmaxf(tm0, h0); tm1 = fmaxf(tm1, h1v); }
                }
                tm0 = fmaxf(tm0, __shfl_xor(tm0, 16, 64));
                tm0 = fmaxf(tm0, __shfl_xor(tm0, 32, 64));
                tm1 = fmaxf(tm1, __shfl_xor(tm1, 16, 64));
                tm1 = fmaxf(tm1, __shfl_xor(tm1, 32, 64));
                pool0 = fmaxf(pool0, tm0);
                pool1 = fmaxf(pool1, tm1);
            }

            if (vb) { pa0 = pb0; pa1 = pb1; }
            va = vb;
            // next x_lds write is safe: GEMM1 readers fenced by the 2nd BARRIER_LDS
        }

        // ---- row epilogue: pool -> LN2 -> fc (LDS-only barriers keep prefetch alive)
        if (l < 16) {
            pool_lds[w * 32 + ln]      = pool0;
            pool_lds[w * 32 + 16 + ln] = pool1;
        }
        BARRIER_LDS();

        float v0 = pool_lds[l], v1 = pool_lds[l + 64];
        float s = v0 + v1, ss = v0 * v0 + v1 * v1;
        #pragma unroll
        for (int m = 1; m < 64; m <<= 1) {
            s  += __shfl_xor(s,  m, 64);
            ss += __shfl_xor(ss, m, 64);
        }
        float mu  = s * (1.f / 128.f);
        float var = ss * (1.f / 128.f) - mu * mu;
        float rs  = rsqrtf(var + 1e-12f);
        float n0 = (v0 - mu) * rs * g2a + b2a;
        float n1 = (v1 - mu) * rs * g2c + b2c;
        float dot = n0 * fwa + n1 * fwc;
        #pragma unroll
        for (int m = 1; m < 64; m <<= 1) dot += __shfl_xor(dot, m, 64);
        if (tid == 0) out[r] = dot + fcb0;

        BARRIER_LDS();   // protect pool_lds before next row's writes
    }
}

extern "C" void kernel_launch(void* const* d_in, const int* in_sizes, int n_in,
                              void* d_out, int out_size, void* d_ws, size_t ws_size,
                              hipStream_t stream) {
    const int*   ids  = (const int*)d_in[0];
    const int*   lens = (const int*)d_in[1];
    const float* emb  = (const float*)d_in[2];
    const float* ln1g = (const float*)d_in[3];
    const float* ln1b = (const float*)d_in[4];
    const float* w1   = (const float*)d_in[5];
    const float* b1   = (const float*)d_in[6];
    const float* w2   = (const float*)d_in[7];
    const float* b2   = (const float*)d_in[8];
    const float* ln2g = (const float*)d_in[9];
    const float* ln2b = (const float*)d_in[10];
    const float* fcw  = (const float*)d_in[11];
    const float* fcb  = (const float*)d_in[12];
    float* out = (float*)d_out;
    short8* ws = (short8*)d_ws;   // needs 128 KiB

    hipLaunchKernelGGL(prep_weights, dim3(32), dim3(256), 0, stream, w1, w2, ws);

    int nblocks = out_size / NR;   // 1024 persistent blocks, 4 strided rows each
    hipLaunchKernelGGL(entity_encoder_kernel, dim3(nblocks), dim3(256), 0, stream,
                       ids, lens, emb, ln1g, ln1b, b1, b2, ln2g, ln2b, fcw, fcb,
                       ws, out);
}

// Round 9
// 69.848 us; speedup vs baseline: 1.3659x; 1.0081x over previous
//
#include <hip/hip_runtime.h>
#include <hip/hip_bf16.h>
#include <math.h>

typedef __attribute__((ext_vector_type(8))) _Float16 half8;
typedef __attribute__((ext_vector_type(4))) float f32x4;

#define EMBD 128
#define H1 256
#define H2 128
#define SLEN 50
#define NR 4            // rows per block (grid = 4096/NR = 1024)

// Branch-free GELU, exact-erf form via Abramowitz-Stegun 7.1.26 (|err|<=1.5e-7).
__device__ __forceinline__ float gelu_exact(float h) {
    float ah = fabsf(h);
    float d  = fmaf(0.23163845f, ah, 1.0f);
    float t;
    asm("v_rcp_f32 %0, %1" : "=v"(t) : "v"(d));
    float p = fmaf(1.061405429f, t, -1.453152027f);
    p = fmaf(p, t, 1.421413741f);
    p = fmaf(p, t, -0.284496736f);
    p = fmaf(p, t, 0.254829592f);
    p = p * t;
    float e;                                   // v_exp_f32 computes 2^x
    float x2 = h * h * -0.72134752f;           // -h^2/2 * log2(e)
    asm("v_exp_f32 %0, %1" : "=v"(e) : "v"(x2));
    float er = fmaf(-p, e, 1.0f);
    return fmaf(0.5f * ah, er, 0.5f * h);
}

// Raw barrier WITHOUT vmcnt drain: LDS ordering only (lgkmcnt), so in-flight
// global prefetches survive the barrier.
#define BARRIER_LDS() asm volatile("s_waitcnt lgkmcnt(0)\n\ts_barrier" ::: "memory")

// ---------------------------------------------------------------------------
// Prep: w1/w2 fp32 row-major -> fp16 MFMA B-fragments (layout as in R3).
// ---------------------------------------------------------------------------
__global__ __launch_bounds__(256) void prep_weights(
    const float* __restrict__ w1, const float* __restrict__ w2,
    half8* __restrict__ ws)
{
    int f = blockIdx.x * 256 + threadIdx.x;   // 0..8191
    half8 v;
    if (f < 4096) {
        int lane = f & 63;
        int nt = (f >> 6) & 3, kt = (f >> 8) & 3, w = (f >> 10) & 3;
        int col = w * 64 + nt * 16 + (lane & 15);
        int kb  = kt * 32 + (lane >> 4) * 8;
        #pragma unroll
        for (int i = 0; i < 8; ++i) v[i] = (_Float16)w1[(size_t)(kb + i) * H1 + col];
        ws[f] = v;
    } else {
        int f2 = f - 4096;
        int lane = f2 & 63;
        int nt = (f2 >> 6) & 1, kt = (f2 >> 7) & 7, w = (f2 >> 10) & 3;
        int col = w * 32 + nt * 16 + (lane & 15);
        int kb  = kt * 32 + (lane >> 4) * 8;
        #pragma unroll
        for (int i = 0; i < 8; ++i) v[i] = (_Float16)w2[(size_t)(kb + i) * H2 + col];
        ws[4096 + f2] = v;
    }
}

// ---------------------------------------------------------------------------
// Main: 1024 persistent blocks x 256 threads, NR=4 rows each (strided).
// Structure identical to the passing R6 kernel; only operand dtype changed.
// ---------------------------------------------------------------------------
__global__ __launch_bounds__(256) void entity_encoder_kernel(
    const int* __restrict__ ids, const int* __restrict__ lens,
    const float* __restrict__ emb, const float* __restrict__ ln1g,
    const float* __restrict__ ln1b, const float* __restrict__ b1,
    const float* __restrict__ b2, const float* __restrict__ ln2g,
    const float* __restrict__ ln2b, const float* __restrict__ fcw,
    const float* __restrict__ fcb, const half8* __restrict__ wfrag,
    float* __restrict__ out)
{
    const int tid = threadIdx.x;
    const int w  = tid >> 6;   // wave 0..3
    const int l  = tid & 63;   // lane
    const int ln = l & 15;
    const int lg = l >> 4;

    __shared__ __align__(16) _Float16 x_lds[16][EMBD + 8];
    __shared__ __align__(16) _Float16 h1_lds[16][H1 + 8];
    __shared__ float pool_lds[H2];

    // ---- weight fragments: 32 coalesced 16B loads, once per block (4 rows) ----
    half8 w1f[4][4];
    #pragma unroll
    for (int kt = 0; kt < 4; ++kt)
      #pragma unroll
      for (int nt = 0; nt < 4; ++nt)
        w1f[kt][nt] = wfrag[((w * 4 + kt) * 4 + nt) * 64 + l];
    half8 w2f[8][2];
    #pragma unroll
    for (int kt = 0; kt < 8; ++kt)
      #pragma unroll
      for (int nt = 0; nt < 2; ++nt)
        w2f[kt][nt] = wfrag[4096 + ((w * 8 + kt) * 2 + nt) * 64 + l];

    float g1r[8], b1r[8];
    #pragma unroll
    for (int i = 0; i < 8; ++i) { g1r[i] = ln1g[ln * 8 + i]; b1r[i] = ln1b[ln * 8 + i]; }
    float b1v[4];
    #pragma unroll
    for (int nt = 0; nt < 4; ++nt) b1v[nt] = b1[w * 64 + nt * 16 + ln];
    float b2v[2];
    #pragma unroll
    for (int nt = 0; nt < 2; ++nt) b2v[nt] = b2[w * 32 + nt * 16 + ln];
    float g2a = ln2g[l], g2c = ln2g[l + 64];
    float b2a = ln2b[l], b2c = ln2b[l + 64];
    float fwa = fcw[l],  fwc = fcw[l + 64];
    float fcb0 = fcb[0];

    const int stride = gridDim.x;              // 1024
    const int tok = w * 4 + lg;                // token-in-tile of this 16-lane group

    // ---- per-block row list + lengths (uniform scalar loads) ----
    int rows[NR], Ts[NR];
    #pragma unroll
    for (int i = 0; i < NR; ++i) {
        rows[i] = blockIdx.x + i * stride;
        int T = lens[rows[i]];
        Ts[i] = T < 1 ? 1 : (T > SLEN ? SLEN : T);
    }

    // ---- prefetch row 0, tile 0 ----
    float4 pa0, pa1; bool va;
    {
        va = (tok < Ts[0]);
        if (va) {
            int id = ids[rows[0] * SLEN + tok];
            const float4* src = (const float4*)(emb + (size_t)id * EMBD + ln * 8);
            pa0 = src[0]; pa1 = src[1];
        }
    }

    for (int i = 0; i < NR; ++i) {
        const int r = rows[i];
        const int T = Ts[i];
        const int ntiles = (T + 15) >> 4;
        float pool0 = -INFINITY, pool1 = -INFINITY;

        for (int mt = 0; mt < ntiles; ++mt) {
            // ---- LN1 on prefetched tile -> fp16 -> x_lds ----
            half8 xo;
            if (va) {
                float v[8] = {pa0.x, pa0.y, pa0.z, pa0.w, pa1.x, pa1.y, pa1.z, pa1.w};
                float s = 0.f, ss = 0.f;
                #pragma unroll
                for (int k = 0; k < 8; ++k) { s += v[k]; ss += v[k] * v[k]; }
                #pragma unroll
                for (int m = 1; m < 16; m <<= 1) {
                    s  += __shfl_xor(s,  m, 64);
                    ss += __shfl_xor(ss, m, 64);
                }
                float mu  = s * (1.f / 128.f);
                float var = ss * (1.f / 128.f) - mu * mu;
                float rs  = rsqrtf(var + 1e-12f);
                #pragma unroll
                for (int k = 0; k < 8; ++k)
                    xo[k] = (_Float16)((v[k] - mu) * rs * g1r[k] + b1r[k]);
            } else {
                #pragma unroll
                for (int k = 0; k < 8; ++k) xo[k] = (_Float16)0.f;
            }
            *(half8*)&x_lds[tok][ln * 8] = xo;

            // ---- issue next gather: tile mt+1 of this row, else tile 0 of next row ----
            float4 pb0, pb1; bool vb = false;
            {
                int ni = i, nmt = mt + 1;
                if (nmt >= ntiles) { ni = i + 1; nmt = 0; }
                if (ni < NR) {
                    int tn = nmt * 16 + tok;
                    if (tn < Ts[ni]) {
                        vb = true;
                        int id = ids[rows[ni] * SLEN + tn];
                        const float4* src = (const float4*)(emb + (size_t)id * EMBD + ln * 8);
                        pb0 = src[0]; pb1 = src[1];
                    }
                }
            }

            BARRIER_LDS();   // x_lds ready (no vmcnt drain)

            // ---- GEMM1: wave w computes cols w*64..w*64+63 ----
            f32x4 acc[4] = {{0,0,0,0},{0,0,0,0},{0,0,0,0},{0,0,0,0}};
            #pragma unroll
            for (int kt = 0; kt < 4; ++kt) {
                half8 a = *(const half8*)&x_lds[ln][kt * 32 + lg * 8];
                #pragma unroll
                for (int nt = 0; nt < 4; ++nt)
                    acc[nt] = __builtin_amdgcn_mfma_f32_16x16x32_f16(a, w1f[kt][nt], acc[nt], 0, 0, 0);
            }
            // bias + branch-free exact-erf GELU -> h1_lds (fp16)
            #pragma unroll
            for (int nt = 0; nt < 4; ++nt) {
                int col = w * 64 + nt * 16 + ln;
                #pragma unroll
                for (int g2 = 0; g2 < 4; ++g2) {
                    int row = lg * 4 + g2;
                    float h = acc[nt][g2] + b1v[nt];
                    h1_lds[row][col] = (_Float16)gelu_exact(h);
                }
            }

            BARRIER_LDS();   // h1_lds ready (no vmcnt drain)

            // ---- GEMM2: wave w computes cols w*32..w*32+31 ----
            f32x4 acc2[2] = {{0,0,0,0},{0,0,0,0}};
            #pragma unroll
            for (int kt = 0; kt < 8; ++kt) {
                half8 a = *(const half8*)&h1_lds[ln][kt * 32 + lg * 8];
                #pragma unroll
                for (int nt = 0; nt < 2; ++nt)
                    acc2[nt] = __builtin_amdgcn_mfma_f32_16x16x32_f16(a, w2f[kt][nt], acc2[nt], 0, 0, 0);
            }
            // ---- masked max-pool (token = lg*4+g2) ----
            {
                float tm0 = -INFINITY, tm1 = -INFINITY;
                #pragma unroll
                for (int g2 = 0; g2 < 4; ++g2) {
                    int trow = lg * 4 + g2;
                    bool valid = (mt * 16 + trow) < T;
                    float h0  = acc2[0][g2] + b2v[0];
                    float h1v = acc2[1][g2] + b2v[1];
                    if (valid) { tm0 = fmaxf(tm0, h0); tm1 = fmaxf(tm1, h1v); }
                }
                tm0 = fmaxf(tm0, __shfl_xor(tm0, 16, 64));
                tm0 = fmaxf(tm0, __shfl_xor(tm0, 32, 64));
                tm1 = fmaxf(tm1, __shfl_xor(tm1, 16, 64));
                tm1 = fmaxf(tm1, __shfl_xor(tm1, 32, 64));
                pool0 = fmaxf(pool0, tm0);
                pool1 = fmaxf(pool1, tm1);
            }

            if (vb) { pa0 = pb0; pa1 = pb1; }
            va = vb;
            // next x_lds write is safe: GEMM1 readers fenced by the 2nd BARRIER_LDS
        }

        // ---- row epilogue: pool -> LN2 -> fc (LDS-only barriers keep prefetch alive)
        if (l < 16) {
            pool_lds[w * 32 + ln]      = pool0;
            pool_lds[w * 32 + 16 + ln] = pool1;
        }
        BARRIER_LDS();

        float v0 = pool_lds[l], v1 = pool_lds[l + 64];
        float s = v0 + v1, ss = v0 * v0 + v1 * v1;
        #pragma unroll
        for (int m = 1; m < 64; m <<= 1) {
            s  += __shfl_xor(s,  m, 64);
            ss += __shfl_xor(ss, m, 64);
        }
        float mu  = s * (1.f / 128.f);
        float var = ss * (1.f / 128.f) - mu * mu;
        float rs  = rsqrtf(var + 1e-12f);
        float n0 = (v0 - mu) * rs * g2a + b2a;
        float n1 = (v1 - mu) * rs * g2c + b2c;
        float dot = n0 * fwa + n1 * fwc;
        #pragma unroll
        for (int m = 1; m < 64; m <<= 1) dot += __shfl_xor(dot, m, 64);
        if (tid == 0) out[r] = dot + fcb0;

        BARRIER_LDS();   // protect pool_lds before next row's writes
    }
}

extern "C" void kernel_launch(void* const* d_in, const int* in_sizes, int n_in,
                              void* d_out, int out_size, void* d_ws, size_t ws_size,
                              hipStream_t stream) {
    const int*   ids  = (const int*)d_in[0];
    const int*   lens = (const int*)d_in[1];
    const float* emb  = (const float*)d_in[2];
    const float* ln1g = (const float*)d_in[3];
    const float* ln1b = (const float*)d_in[4];
    const float* w1   = (const float*)d_in[5];
    const float* b1   = (const float*)d_in[6];
    const float* w2   = (const float*)d_in[7];
    const float* b2   = (const float*)d_in[8];
    const float* ln2g = (const float*)d_in[9];
    const float* ln2b = (const float*)d_in[10];
    const float* fcw  = (const float*)d_in[11];
    const float* fcb  = (const float*)d_in[12];
    float* out = (float*)d_out;
    half8* ws = (half8*)d_ws;   // needs 128 KiB

    hipLaunchKernelGGL(prep_weights, dim3(32), dim3(256), 0, stream, w1, w2, ws);

    int nblocks = out_size / NR;   // 1024 persistent blocks, 4 strided rows each
    hipLaunchKernelGGL(entity_encoder_kernel, dim3(nblocks), dim3(256), 0, stream,
                       ids, lens, emb, ln1g, ln1b, b1, b2, ln2g, ln2b, fcw, fcb,
                       ws, out);
}